// Round 1
// baseline (339.714 us; speedup 1.0000x reference)
//
#include <hip/hip_runtime.h>
#include <cmath>

// Problem constants (fixed by setup_inputs)
#define NB   8      // batch
#define NN   1024   // nodes
#define DIN  256
#define DOUT 256
#define NH   8      // heads
#define DH   32     // head dim
constexpr float LN_EPS   = 1e-5f;
constexpr float QK_SCALE = 0.17677669529663687f; // 1/sqrt(32)

// ---------------------------------------------------------------------------
// Kernel A: fused QKV projection.  X:(8192,256) @ {Wq,Wk,Wv}:(256,256) + bias
// -> Q,K,V stored (B,H,N,DH).  64x64 output tile per block, 256 thr, 4x4 micro.
// X tile staged transposed in LDS so fragments are contiguous float4 reads.
// ---------------------------------------------------------------------------
__global__ __launch_bounds__(256) void qkv_kernel(
    const float* __restrict__ X,
    const float* __restrict__ Wq, const float* __restrict__ bq,
    const float* __restrict__ Wk, const float* __restrict__ bk,
    const float* __restrict__ Wv, const float* __restrict__ bv,
    float* __restrict__ Qo, float* __restrict__ Ko, float* __restrict__ Vo)
{
    const int m0 = blockIdx.x * 64;
    const int n0 = blockIdx.y * 64;
    const int t  = threadIdx.x;
    const int tc = t & 15, tr = t >> 4;

    __shared__ float Xs[32][68];      // [k][m] transposed
    __shared__ float Ws[3][32][68];   // [k][n] natural

    float acc[3][4][4];
#pragma unroll
    for (int j = 0; j < 4; ++j) {
        float b0 = bq[n0 + tc*4 + j];
        float b1 = bk[n0 + tc*4 + j];
        float b2 = bv[n0 + tc*4 + j];
#pragma unroll
        for (int i = 0; i < 4; ++i) { acc[0][i][j] = b0; acc[1][i][j] = b1; acc[2][i][j] = b2; }
    }

    const int xrow = t >> 2, xseg = (t & 3) * 8;   // X tile loader: 64 rows x 32 k
    const int wrow = t >> 3, wseg = (t & 7) * 8;   // W tile loader: 32 k x 64 n

    for (int k0 = 0; k0 < DIN; k0 += 32) {
        __syncthreads();
        {   // stage X transposed
            const float* src = X + (m0 + xrow) * DIN + k0 + xseg;
            float tmp[8];
            *(float4*)&tmp[0] = *(const float4*)(src);
            *(float4*)&tmp[4] = *(const float4*)(src + 4);
#pragma unroll
            for (int c = 0; c < 8; ++c) Xs[xseg + c][xrow] = tmp[c];
        }
#pragma unroll
        for (int w = 0; w < 3; ++w) {   // stage W natural
            const float* Wp  = (w == 0) ? Wq : (w == 1) ? Wk : Wv;
            const float* src = Wp + (k0 + wrow) * DOUT + n0 + wseg;
            *(float4*)&Ws[w][wrow][wseg]     = *(const float4*)(src);
            *(float4*)&Ws[w][wrow][wseg + 4] = *(const float4*)(src + 4);
        }
        __syncthreads();
#pragma unroll
        for (int kk = 0; kk < 32; ++kk) {
            float4 x4 = *(const float4*)&Xs[kk][tr*4];
            float xr[4] = {x4.x, x4.y, x4.z, x4.w};
#pragma unroll
            for (int w = 0; w < 3; ++w) {
                float4 w4 = *(const float4*)&Ws[w][kk][tc*4];
                float wr[4] = {w4.x, w4.y, w4.z, w4.w};
#pragma unroll
                for (int i = 0; i < 4; ++i)
#pragma unroll
                    for (int j = 0; j < 4; ++j)
                        acc[w][i][j] = fmaf(xr[i], wr[j], acc[w][i][j]);
            }
        }
    }

    // write out to (B,H,N,DH); 4 consecutive cols never cross a head boundary
    const int c0 = n0 + tc*4;
    const int h = c0 >> 5, d0 = c0 & 31;
#pragma unroll
    for (int i = 0; i < 4; ++i) {
        int row = m0 + tr*4 + i;
        int b = row >> 10, n = row & (NN - 1);
        int base = ((b*NH + h)*NN + n)*DH + d0;
        *(float4*)&Qo[base] = make_float4(acc[0][i][0], acc[0][i][1], acc[0][i][2], acc[0][i][3]);
        *(float4*)&Ko[base] = make_float4(acc[1][i][0], acc[1][i][1], acc[1][i][2], acc[1][i][3]);
        *(float4*)&Vo[base] = make_float4(acc[2][i][0], acc[2][i][1], acc[2][i][2], acc[2][i][3]);
    }
}

// ---------------------------------------------------------------------------
// Kernel B: flash attention per (b, h, 64-query tile).  Online softmax.
// scores = (Q/sqrt(D)) K^T + edge*We[h] + be[h]
// Thread map: tc=t&15 (cols / d-pairs), tr=t>>4 (4 q-rows each).
// Row softmax reduction across 16 consecutive lanes via shfl_xor.
// ---------------------------------------------------------------------------
__global__ __launch_bounds__(256) void attn_kernel(
    const float* __restrict__ Qg, const float* __restrict__ Kg, const float* __restrict__ Vg,
    const float* __restrict__ Eg,
    const float* __restrict__ We, const float* __restrict__ be,
    float* __restrict__ AO)
{
    const int bid = blockIdx.x;
    const int qt = bid & 15;
    const int h  = (bid >> 4) & 7;
    const int b  = bid >> 7;
    const int q0 = qt * 64;
    const int t  = threadIdx.x;
    const int tc = t & 15, tr = t >> 4;

    __shared__ float Qs[32][68];   // [d][q] transposed, pre-scaled
    __shared__ float Ks[32][68];   // [d][c] transposed
    __shared__ float Vs[64][36];   // [c][d] natural (stride 36 -> 16B aligned rows)
    __shared__ float Ps[64][68];   // [c][q] transposed P

    const float we_h = We[h];
    const float be_h = be[h];
    const int bh = (b*NH + h) * NN * DH;

    const int srow = t >> 2, sseg = (t & 3) * 8;

    {   // Q tile -> LDS transposed, pre-scaled by 1/sqrt(D)
        const float* src = Qg + bh + (q0 + srow)*DH + sseg;
        float tmp[8];
        *(float4*)&tmp[0] = *(const float4*)(src);
        *(float4*)&tmp[4] = *(const float4*)(src + 4);
#pragma unroll
        for (int c = 0; c < 8; ++c) Qs[sseg + c][srow] = tmp[c] * QK_SCALE;
    }

    float m_r[4], l_r[4], Oa[4][2];
#pragma unroll
    for (int i = 0; i < 4; ++i) { m_r[i] = -3.0e38f; l_r[i] = 0.f; Oa[i][0] = 0.f; Oa[i][1] = 0.f; }

    const float* erow0 = Eg + b*NN*NN + (q0 + tr*4)*NN + tc*4;

    for (int kt = 0; kt < 16; ++kt) {
        const int m0 = kt * 64;
        __syncthreads();   // prev GEMM2 done (protects Vs/Ps); iter0: Qs visible
        {   // stage K (transposed) and V (natural)
            const float* srck = Kg + bh + (m0 + srow)*DH + sseg;
            float tmpk[8];
            *(float4*)&tmpk[0] = *(const float4*)(srck);
            *(float4*)&tmpk[4] = *(const float4*)(srck + 4);
            const float* srcv = Vg + bh + (m0 + srow)*DH + sseg;
            float4 v0 = *(const float4*)(srcv);
            float4 v1 = *(const float4*)(srcv + 4);
#pragma unroll
            for (int c = 0; c < 8; ++c) Ks[sseg + c][srow] = tmpk[c];
            *(float4*)&Vs[srow][sseg]     = v0;
            *(float4*)&Vs[srow][sseg + 4] = v1;
        }
        __syncthreads();

        // GEMM1: S = Q K^T  (pre-scaled)
        float s[4][4];
#pragma unroll
        for (int i = 0; i < 4; ++i)
#pragma unroll
            for (int j = 0; j < 4; ++j) s[i][j] = 0.f;
#pragma unroll
        for (int d = 0; d < 32; ++d) {
            float4 q4 = *(const float4*)&Qs[d][tr*4];
            float4 k4 = *(const float4*)&Ks[d][tc*4];
            float qr[4] = {q4.x, q4.y, q4.z, q4.w};
            float kr[4] = {k4.x, k4.y, k4.z, k4.w};
#pragma unroll
            for (int i = 0; i < 4; ++i)
#pragma unroll
                for (int j = 0; j < 4; ++j)
                    s[i][j] = fmaf(qr[i], kr[j], s[i][j]);
        }

        // edge bias (L3-resident global reads, 16B per lane per row)
#pragma unroll
        for (int i = 0; i < 4; ++i) {
            float4 e4 = *(const float4*)(erow0 + i*NN + m0);
            s[i][0] = fmaf(e4.x, we_h, s[i][0]) + be_h;
            s[i][1] = fmaf(e4.y, we_h, s[i][1]) + be_h;
            s[i][2] = fmaf(e4.z, we_h, s[i][2]) + be_h;
            s[i][3] = fmaf(e4.w, we_h, s[i][3]) + be_h;
        }

        // online softmax (row spread over 16 lanes: xor masks 1,2,4,8)
#pragma unroll
        for (int i = 0; i < 4; ++i) {
            float tm = fmaxf(fmaxf(s[i][0], s[i][1]), fmaxf(s[i][2], s[i][3]));
            tm = fmaxf(tm, __shfl_xor(tm, 1));
            tm = fmaxf(tm, __shfl_xor(tm, 2));
            tm = fmaxf(tm, __shfl_xor(tm, 4));
            tm = fmaxf(tm, __shfl_xor(tm, 8));
            float mn = fmaxf(m_r[i], tm);
            float alpha = __expf(m_r[i] - mn);
            float ps = 0.f;
#pragma unroll
            for (int j = 0; j < 4; ++j) { s[i][j] = __expf(s[i][j] - mn); ps += s[i][j]; }
            ps += __shfl_xor(ps, 1);
            ps += __shfl_xor(ps, 2);
            ps += __shfl_xor(ps, 4);
            ps += __shfl_xor(ps, 8);
            l_r[i] = l_r[i] * alpha + ps;
            m_r[i] = mn;
            Oa[i][0] *= alpha; Oa[i][1] *= alpha;
        }

        // store P transposed for GEMM2
#pragma unroll
        for (int j = 0; j < 4; ++j)
#pragma unroll
            for (int i = 0; i < 4; ++i)
                Ps[tc*4 + j][tr*4 + i] = s[i][j];
        __syncthreads();

        // GEMM2: O += P @ V   (thread owns 4 q-rows x 2 d-cols)
#pragma unroll
        for (int c = 0; c < 64; ++c) {
            float4 p4 = *(const float4*)&Ps[c][tr*4];
            float2 v2 = *(const float2*)&Vs[c][tc*2];
            Oa[0][0] = fmaf(p4.x, v2.x, Oa[0][0]);
            Oa[0][1] = fmaf(p4.x, v2.y, Oa[0][1]);
            Oa[1][0] = fmaf(p4.y, v2.x, Oa[1][0]);
            Oa[1][1] = fmaf(p4.y, v2.y, Oa[1][1]);
            Oa[2][0] = fmaf(p4.z, v2.x, Oa[2][0]);
            Oa[2][1] = fmaf(p4.z, v2.y, Oa[2][1]);
            Oa[3][0] = fmaf(p4.w, v2.x, Oa[3][0]);
            Oa[3][1] = fmaf(p4.w, v2.y, Oa[3][1]);
        }
    }

    // epilogue: normalize and write (B,N,H*DH)
#pragma unroll
    for (int i = 0; i < 4; ++i) {
        float inv = 1.0f / l_r[i];
        int qg = q0 + tr*4 + i;
        float2 o2 = make_float2(Oa[i][0] * inv, Oa[i][1] * inv);
        *(float2*)&AO[(b*NN + qg)*DOUT + h*DH + tc*2] = o2;
    }
}

// ---------------------------------------------------------------------------
// Kernel C: out projection + bias + residual -> d_out (pre-LN x)
// ---------------------------------------------------------------------------
__global__ __launch_bounds__(256) void oproj_kernel(
    const float* __restrict__ A,
    const float* __restrict__ Wo, const float* __restrict__ bo,
    const float* __restrict__ X0,
    float* __restrict__ Y)
{
    const int m0 = blockIdx.x * 64;
    const int n0 = blockIdx.y * 64;
    const int t  = threadIdx.x;
    const int tc = t & 15, tr = t >> 4;

    __shared__ float As[32][68];
    __shared__ float Ws[32][68];

    float acc[4][4];
#pragma unroll
    for (int j = 0; j < 4; ++j) {
        float b0 = bo[n0 + tc*4 + j];
#pragma unroll
        for (int i = 0; i < 4; ++i) acc[i][j] = b0;
    }

    const int xrow = t >> 2, xseg = (t & 3) * 8;
    const int wrow = t >> 3, wseg = (t & 7) * 8;

    for (int k0 = 0; k0 < DOUT; k0 += 32) {
        __syncthreads();
        {
            const float* src = A + (m0 + xrow)*DOUT + k0 + xseg;
            float tmp[8];
            *(float4*)&tmp[0] = *(const float4*)(src);
            *(float4*)&tmp[4] = *(const float4*)(src + 4);
#pragma unroll
            for (int c = 0; c < 8; ++c) As[xseg + c][xrow] = tmp[c];
        }
        {
            const float* src = Wo + (k0 + wrow)*DOUT + n0 + wseg;
            *(float4*)&Ws[wrow][wseg]     = *(const float4*)(src);
            *(float4*)&Ws[wrow][wseg + 4] = *(const float4*)(src + 4);
        }
        __syncthreads();
#pragma unroll
        for (int kk = 0; kk < 32; ++kk) {
            float4 x4 = *(const float4*)&As[kk][tr*4];
            float4 w4 = *(const float4*)&Ws[kk][tc*4];
            float xr[4] = {x4.x, x4.y, x4.z, x4.w};
            float wr[4] = {w4.x, w4.y, w4.z, w4.w};
#pragma unroll
            for (int i = 0; i < 4; ++i)
#pragma unroll
                for (int j = 0; j < 4; ++j)
                    acc[i][j] = fmaf(xr[i], wr[j], acc[i][j]);
        }
    }

#pragma unroll
    for (int i = 0; i < 4; ++i) {
        int row = m0 + tr*4 + i;
        float4 r4 = *(const float4*)&X0[row*DIN + n0 + tc*4];
        float4 o;
        o.x = acc[i][0] + r4.x;
        o.y = acc[i][1] + r4.y;
        o.z = acc[i][2] + r4.z;
        o.w = acc[i][3] + r4.w;
        *(float4*)&Y[row*DOUT + n0 + tc*4] = o;
    }
}

// ---------------------------------------------------------------------------
// Kernel D: in-place LayerNorm, one wave per row, two-pass (exact variance)
// ---------------------------------------------------------------------------
__global__ __launch_bounds__(64) void ln_kernel(
    float* __restrict__ X, const float* __restrict__ g, const float* __restrict__ bta)
{
    const int row = blockIdx.x;
    const int l = threadIdx.x;
    float4 v = *(const float4*)&X[row*DOUT + l*4];

    float s = v.x + v.y + v.z + v.w;
#pragma unroll
    for (int m = 1; m < 64; m <<= 1) s += __shfl_xor(s, m);
    float mu = s * (1.0f / 256.0f);

    float dx = v.x - mu, dy = v.y - mu, dz = v.z - mu, dw = v.w - mu;
    float ss = dx*dx + dy*dy + dz*dz + dw*dw;
#pragma unroll
    for (int m = 1; m < 64; m <<= 1) ss += __shfl_xor(ss, m);
    float r = rsqrtf(ss * (1.0f / 256.0f) + LN_EPS);

    float4 g4 = *(const float4*)&g[l*4];
    float4 b4 = *(const float4*)&bta[l*4];
    float4 o;
    o.x = dx * r * g4.x + b4.x;
    o.y = dy * r * g4.y + b4.y;
    o.z = dz * r * g4.z + b4.z;
    o.w = dw * r * g4.w + b4.w;
    *(float4*)&X[row*DOUT + l*4] = o;
}

// ---------------------------------------------------------------------------
extern "C" void kernel_launch(void* const* d_in, const int* in_sizes, int n_in,
                              void* d_out, int out_size, void* d_ws, size_t ws_size,
                              hipStream_t stream) {
    const float* X    = (const float*)d_in[0];
    const float* E    = (const float*)d_in[1];
    const float* Wq   = (const float*)d_in[2];
    const float* bq   = (const float*)d_in[3];
    const float* Wk   = (const float*)d_in[4];
    const float* bk   = (const float*)d_in[5];
    const float* Wv   = (const float*)d_in[6];
    const float* bv   = (const float*)d_in[7];
    const float* We   = (const float*)d_in[8];
    const float* be   = (const float*)d_in[9];
    const float* Wo   = (const float*)d_in[10];
    const float* bo   = (const float*)d_in[11];
    const float* gam  = (const float*)d_in[12];
    const float* bet  = (const float*)d_in[13];
    float* out = (float*)d_out;

    // workspace: Q,K,V,(B,H,N,DH) + attn_out (B,N,256) = 32 MB fp32
    const int TENS = NB * NN * DOUT;   // 2097152
    float* Qw = (float*)d_ws;
    float* Kw = Qw + TENS;
    float* Vw = Kw + TENS;
    float* AO = Vw + TENS;

    dim3 gA(NB*NN/64, DOUT/64);
    qkv_kernel<<<gA, 256, 0, stream>>>(X, Wq, bq, Wk, bk, Wv, bv, Qw, Kw, Vw);

    attn_kernel<<<NB*NH*(NN/64), 256, 0, stream>>>(Qw, Kw, Vw, E, We, be, AO);

    dim3 gC(NB*NN/64, DOUT/64);
    oproj_kernel<<<gC, 256, 0, stream>>>(AO, Wo, bo, X, out);

    ln_kernel<<<NB*NN, 64, 0, stream>>>(out, gam, bet);
}

// Round 2
// 211.018 us; speedup vs baseline: 1.6099x; 1.6099x over previous
//
#include <hip/hip_runtime.h>

// Problem constants (fixed by setup_inputs)
#define NB   8      // batch
#define NN   1024   // nodes
#define DIN  256
#define DOUT 256
#define NH   8      // heads
#define DH   32     // head dim
constexpr float LN_EPS   = 1e-5f;
constexpr float QK_SCALE = 0.17677669529663687f; // 1/sqrt(32)

typedef __attribute__((ext_vector_type(8))) short s16x8;   // 8 bf16 (4 VGPR)
typedef __attribute__((ext_vector_type(4))) float f32x4;   // MFMA acc

__device__ __forceinline__ unsigned short f2bf(float f) {  // RNE fp32->bf16
    unsigned int u = __float_as_uint(f);
    u += 0x7FFFu + ((u >> 16) & 1u);
    return (unsigned short)(u >> 16);
}
__device__ __forceinline__ float bf2f(unsigned short h) {
    return __uint_as_float(((unsigned int)h) << 16);
}
__device__ __forceinline__ unsigned int packbf(float a, float b) {
    return (unsigned int)f2bf(a) | ((unsigned int)f2bf(b) << 16);
}

// ---------------------------------------------------------------------------
// Kernel A: fused QKV projection.  X:(8192,256) @ {Wq,Wk,Wv}:(256,256) + bias
// Outputs: Qhi/Qlo (split bf16, scale folded), K bf16  -- all (B,H,N,DH)
//          V fp32 (B,H,N,DH) for the transpose pass.
// ---------------------------------------------------------------------------
__global__ __launch_bounds__(256) void qkv_kernel(
    const float* __restrict__ X,
    const float* __restrict__ Wq, const float* __restrict__ bq,
    const float* __restrict__ Wk, const float* __restrict__ bk,
    const float* __restrict__ Wv, const float* __restrict__ bv,
    unsigned short* __restrict__ Qhig, unsigned short* __restrict__ Qlog,
    unsigned short* __restrict__ Kbg,  float* __restrict__ Vf)
{
    const int m0 = blockIdx.x * 64;
    const int n0 = blockIdx.y * 64;
    const int t  = threadIdx.x;
    const int tc = t & 15, tr = t >> 4;

    __shared__ float Xs[32][68];      // [k][m] transposed
    __shared__ float Ws[3][32][68];   // [k][n] natural

    float acc[3][4][4];
#pragma unroll
    for (int j = 0; j < 4; ++j) {
        float b0 = bq[n0 + tc*4 + j];
        float b1 = bk[n0 + tc*4 + j];
        float b2 = bv[n0 + tc*4 + j];
#pragma unroll
        for (int i = 0; i < 4; ++i) { acc[0][i][j] = b0; acc[1][i][j] = b1; acc[2][i][j] = b2; }
    }

    const int xrow = t >> 2, xseg = (t & 3) * 8;
    const int wrow = t >> 3, wseg = (t & 7) * 8;

    for (int k0 = 0; k0 < DIN; k0 += 32) {
        __syncthreads();
        {   // stage X transposed
            const float* src = X + (m0 + xrow) * DIN + k0 + xseg;
            float tmp[8];
            *(float4*)&tmp[0] = *(const float4*)(src);
            *(float4*)&tmp[4] = *(const float4*)(src + 4);
#pragma unroll
            for (int c = 0; c < 8; ++c) Xs[xseg + c][xrow] = tmp[c];
        }
#pragma unroll
        for (int w = 0; w < 3; ++w) {
            const float* Wp  = (w == 0) ? Wq : (w == 1) ? Wk : Wv;
            const float* src = Wp + (k0 + wrow) * DOUT + n0 + wseg;
            *(float4*)&Ws[w][wrow][wseg]     = *(const float4*)(src);
            *(float4*)&Ws[w][wrow][wseg + 4] = *(const float4*)(src + 4);
        }
        __syncthreads();
#pragma unroll
        for (int kk = 0; kk < 32; ++kk) {
            float4 x4 = *(const float4*)&Xs[kk][tr*4];
            float xr[4] = {x4.x, x4.y, x4.z, x4.w};
#pragma unroll
            for (int w = 0; w < 3; ++w) {
                float4 w4 = *(const float4*)&Ws[w][kk][tc*4];
                float wr[4] = {w4.x, w4.y, w4.z, w4.w};
#pragma unroll
                for (int i = 0; i < 4; ++i)
#pragma unroll
                    for (int j = 0; j < 4; ++j)
                        acc[w][i][j] = fmaf(xr[i], wr[j], acc[w][i][j]);
            }
        }
    }

    const int c0 = n0 + tc*4;
    const int h = c0 >> 5, d0 = c0 & 31;
#pragma unroll
    for (int i = 0; i < 4; ++i) {
        int row = m0 + tr*4 + i;
        int b = row >> 10, n = row & (NN - 1);
        size_t base = ((size_t)(b*NH + h)*NN + n)*DH + d0;
        ushort4 qh, ql, kb;
#pragma unroll
        for (int j = 0; j < 4; ++j) {
            float q = acc[0][i][j] * QK_SCALE;        // fold 1/sqrt(D) into Q
            unsigned short hb = f2bf(q);
            float lo = q - bf2f(hb);                   // split residual
            ((unsigned short*)&qh)[j] = hb;
            ((unsigned short*)&ql)[j] = f2bf(lo);
            ((unsigned short*)&kb)[j] = f2bf(acc[1][i][j]);
        }
        *(ushort4*)&Qhig[base] = qh;
        *(ushort4*)&Qlog[base] = ql;
        *(ushort4*)&Kbg[base]  = kb;
        *(float4*)&Vf[base] = make_float4(acc[2][i][0], acc[2][i][1], acc[2][i][2], acc[2][i][3]);
    }
}

// ---------------------------------------------------------------------------
// Kernel A2: V fp32 (B,H,N,32) -> Vt bf16 (B,H,32,N)  (for contiguous PV B-frags)
// ---------------------------------------------------------------------------
__global__ __launch_bounds__(256) void vtrans_kernel(
    const float* __restrict__ Vf, unsigned short* __restrict__ Vt)
{
    const int bid = blockIdx.x;
    const int c  = bid & 15;      // 64-key chunk
    const int bh = bid >> 4;      // (b*8+h)
    const int t  = threadIdx.x;
    __shared__ float T[64][33];
    {
        const int n = t >> 2, seg = (t & 3) * 8;
        const float* src = Vf + ((size_t)bh*NN + c*64 + n)*DH + seg;
        float4 a = *(const float4*)src;
        float4 b4 = *(const float4*)(src + 4);
        T[n][seg+0]=a.x;  T[n][seg+1]=a.y;  T[n][seg+2]=a.z;  T[n][seg+3]=a.w;
        T[n][seg+4]=b4.x; T[n][seg+5]=b4.y; T[n][seg+6]=b4.z; T[n][seg+7]=b4.w;
    }
    __syncthreads();
    {
        const int dh = t >> 3, nb = (t & 7) * 8;
        unsigned short o[8];
#pragma unroll
        for (int i = 0; i < 8; ++i) o[i] = f2bf(T[nb + i][dh]);
        *(s16x8*)&Vt[((size_t)bh*DH + dh)*NN + c*64 + nb] = *(const s16x8*)o;
    }
}

// ---------------------------------------------------------------------------
// Kernel B: MFMA flash attention.  Block = (b,h,64-q tile), 4 waves x 16 q.
// Swapped QK^T (A=K, B=Q) -> lane holds q=l&15, 16 keys; softmax reduce over
// {lane^16, lane^32}.  Split-Q 2-term MFMA for fp32-like scores.
// P packed bf16 -> wave-private LDS -> PV MFMA with pre-transposed V.
// Grid decode: b = bid&7 so round-robin XCD placement keeps each batch's 4MB
// E-slice in one XCD's L2 (8 heads re-read the same E rows).
// ---------------------------------------------------------------------------
__global__ __launch_bounds__(256) void attn_kernel(
    const unsigned short* __restrict__ Qhi, const unsigned short* __restrict__ Qlo,
    const unsigned short* __restrict__ Kb,  const unsigned short* __restrict__ Vt,
    const float* __restrict__ Eg, const float* __restrict__ We,
    float* __restrict__ AO)
{
    const int bid = blockIdx.x;
    const int b  = bid & 7;
    const int h  = (bid >> 3) & 7;
    const int qt = bid >> 6;
    const int q0 = qt * 64;
    const int t    = threadIdx.x;
    const int lane = t & 63;
    const int wid  = t >> 6;
    const int l15  = lane & 15;
    const int hi   = lane >> 4;
    const int hi4  = hi * 4;

    __shared__ unsigned short Ks[64][40];      // [key][dh], pitch 40 -> 2-way max
    __shared__ unsigned short Vs[32][72];      // [dh][key], pitch 72
    __shared__ unsigned short Ps[4][16][72];   // per-wave [q][key]

    const float we_h = We[h];
    const size_t kvbase = (size_t)(b*NH + h) * NN * DH;

    // Q fragments: resident in registers for all 16 KV tiles
    const int qrow = q0 + wid*16 + l15;
    const s16x8 qh_f = *(const s16x8*)(Qhi + kvbase + (size_t)qrow*DH + hi*8);
    const s16x8 ql_f = *(const s16x8*)(Qlo + kvbase + (size_t)qrow*DH + hi*8);

    const float* Ep = Eg + ((size_t)b << 20) + ((size_t)qrow << 10);

    const int krow = t >> 2, kseg = (t & 3) * 8;   // K stage: 64 x 32
    const int vrow = t >> 3, vseg = (t & 7) * 8;   // Vt stage: 32 x 64

    float m_run = -3.0e38f, l_run = 0.0f;
    f32x4 Oacc[2];
    Oacc[0] = (f32x4){0.f, 0.f, 0.f, 0.f};
    Oacc[1] = (f32x4){0.f, 0.f, 0.f, 0.f};

    for (int mt = 0; mt < 16; ++mt) {
        const int m0 = mt * 64;
        __syncthreads();   // protect Ks/Vs from previous iteration's readers
        *(s16x8*)&Ks[krow][kseg] = *(const s16x8*)(Kb + kvbase + (size_t)(m0 + krow)*DH + kseg);
        *(s16x8*)&Vs[vrow][vseg] = *(const s16x8*)(Vt + kvbase + (size_t)vrow*NN + m0 + vseg);
        __syncthreads();

        // --- QK^T (swapped): per subtile kt, D[key_local][q], key=kt*16+hi4+r
        float s[16];
#pragma unroll
        for (int kt = 0; kt < 4; ++kt) {
            s16x8 kfr = *(const s16x8*)&Ks[kt*16 + l15][hi*8];
            f32x4 sc = (f32x4){0.f, 0.f, 0.f, 0.f};
            sc = __builtin_amdgcn_mfma_f32_16x16x32_bf16(kfr, ql_f, sc, 0, 0, 0);
            sc = __builtin_amdgcn_mfma_f32_16x16x32_bf16(kfr, qh_f, sc, 0, 0, 0);
            const float4 e4 = *(const float4*)(Ep + m0 + kt*16 + hi4);
            s[kt*4+0] = fmaf(e4.x, we_h, sc[0]);
            s[kt*4+1] = fmaf(e4.y, we_h, sc[1]);
            s[kt*4+2] = fmaf(e4.z, we_h, sc[2]);
            s[kt*4+3] = fmaf(e4.w, we_h, sc[3]);
        }

        // --- online softmax: lane's q = l15; keys split across hi groups
        float tm = s[0];
#pragma unroll
        for (int i = 1; i < 16; ++i) tm = fmaxf(tm, s[i]);
        tm = fmaxf(tm, __shfl_xor(tm, 16));
        tm = fmaxf(tm, __shfl_xor(tm, 32));
        const float mn = fmaxf(m_run, tm);
        const float alpha = __expf(m_run - mn);
        m_run = mn;
        float ps = 0.f;
#pragma unroll
        for (int i = 0; i < 16; ++i) { s[i] = __expf(s[i] - mn); ps += s[i]; }
        ps += __shfl_xor(ps, 16);
        ps += __shfl_xor(ps, 32);
        l_run = l_run * alpha + ps;

        // rescale O (O-layout: lane holds q' = hi4+r, d = l15)
        const float a0 = __shfl(alpha, hi4 + 0);
        const float a1 = __shfl(alpha, hi4 + 1);
        const float a2 = __shfl(alpha, hi4 + 2);
        const float a3 = __shfl(alpha, hi4 + 3);
        Oacc[0][0] *= a0; Oacc[0][1] *= a1; Oacc[0][2] *= a2; Oacc[0][3] *= a3;
        Oacc[1][0] *= a0; Oacc[1][1] *= a1; Oacc[1][2] *= a2; Oacc[1][3] *= a3;

        // --- P -> wave-private LDS (packed bf16, keys reg-adjacent)
#pragma unroll
        for (int kt = 0; kt < 4; ++kt) {
            uint2 w;
            w.x = packbf(s[kt*4+0], s[kt*4+1]);
            w.y = packbf(s[kt*4+2], s[kt*4+3]);
            *(uint2*)&Ps[wid][l15][kt*16 + hi4] = w;
        }

        // --- PV: O[q][d] += P[q][key] * V[key][d]
#pragma unroll
        for (int c = 0; c < 2; ++c) {
            s16x8 pfr = *(const s16x8*)&Ps[wid][l15][c*32 + hi*8];
            s16x8 v0  = *(const s16x8*)&Vs[l15][c*32 + hi*8];
            s16x8 v1  = *(const s16x8*)&Vs[16 + l15][c*32 + hi*8];
            Oacc[0] = __builtin_amdgcn_mfma_f32_16x16x32_bf16(pfr, v0, Oacc[0], 0, 0, 0);
            Oacc[1] = __builtin_amdgcn_mfma_f32_16x16x32_bf16(pfr, v1, Oacc[1], 0, 0, 0);
        }
    }

    // epilogue: normalize, write (B,N,H*DH)
    float linv[4];
#pragma unroll
    for (int r = 0; r < 4; ++r) linv[r] = 1.0f / __shfl(l_run, hi4 + r);
#pragma unroll
    for (int dt = 0; dt < 2; ++dt)
#pragma unroll
        for (int r = 0; r < 4; ++r) {
            int qg = q0 + wid*16 + hi4 + r;
            AO[((size_t)(b*NN + qg))*DOUT + h*DH + dt*16 + l15] = Oacc[dt][r] * linv[r];
        }
}

// ---------------------------------------------------------------------------
// Kernel C: out projection + bias + residual -> d_out (pre-LN x)
// ---------------------------------------------------------------------------
__global__ __launch_bounds__(256) void oproj_kernel(
    const float* __restrict__ A,
    const float* __restrict__ Wo, const float* __restrict__ bo,
    const float* __restrict__ X0,
    float* __restrict__ Y)
{
    const int m0 = blockIdx.x * 64;
    const int n0 = blockIdx.y * 64;
    const int t  = threadIdx.x;
    const int tc = t & 15, tr = t >> 4;

    __shared__ float As[32][68];
    __shared__ float Ws[32][68];

    float acc[4][4];
#pragma unroll
    for (int j = 0; j < 4; ++j) {
        float b0 = bo[n0 + tc*4 + j];
#pragma unroll
        for (int i = 0; i < 4; ++i) acc[i][j] = b0;
    }

    const int xrow = t >> 2, xseg = (t & 3) * 8;
    const int wrow = t >> 3, wseg = (t & 7) * 8;

    for (int k0 = 0; k0 < DOUT; k0 += 32) {
        __syncthreads();
        {
            const float* src = A + (m0 + xrow)*DOUT + k0 + xseg;
            float tmp[8];
            *(float4*)&tmp[0] = *(const float4*)(src);
            *(float4*)&tmp[4] = *(const float4*)(src + 4);
#pragma unroll
            for (int c = 0; c < 8; ++c) As[xseg + c][xrow] = tmp[c];
        }
        {
            const float* src = Wo + (k0 + wrow)*DOUT + n0 + wseg;
            *(float4*)&Ws[wrow][wseg]     = *(const float4*)(src);
            *(float4*)&Ws[wrow][wseg + 4] = *(const float4*)(src + 4);
        }
        __syncthreads();
#pragma unroll
        for (int kk = 0; kk < 32; ++kk) {
            float4 x4 = *(const float4*)&As[kk][tr*4];
            float4 w4 = *(const float4*)&Ws[kk][tc*4];
            float xr[4] = {x4.x, x4.y, x4.z, x4.w};
            float wr[4] = {w4.x, w4.y, w4.z, w4.w};
#pragma unroll
            for (int i = 0; i < 4; ++i)
#pragma unroll
                for (int j = 0; j < 4; ++j)
                    acc[i][j] = fmaf(xr[i], wr[j], acc[i][j]);
        }
    }

#pragma unroll
    for (int i = 0; i < 4; ++i) {
        int row = m0 + tr*4 + i;
        float4 r4 = *(const float4*)&X0[row*DIN + n0 + tc*4];
        float4 o;
        o.x = acc[i][0] + r4.x;
        o.y = acc[i][1] + r4.y;
        o.z = acc[i][2] + r4.z;
        o.w = acc[i][3] + r4.w;
        *(float4*)&Y[row*DOUT + n0 + tc*4] = o;
    }
}

// ---------------------------------------------------------------------------
// Kernel D: in-place LayerNorm, one wave per row
// ---------------------------------------------------------------------------
__global__ __launch_bounds__(64) void ln_kernel(
    float* __restrict__ X, const float* __restrict__ g, const float* __restrict__ bta)
{
    const int row = blockIdx.x;
    const int l = threadIdx.x;
    float4 v = *(const float4*)&X[row*DOUT + l*4];

    float s = v.x + v.y + v.z + v.w;
#pragma unroll
    for (int m = 1; m < 64; m <<= 1) s += __shfl_xor(s, m);
    float mu = s * (1.0f / 256.0f);

    float dx = v.x - mu, dy = v.y - mu, dz = v.z - mu, dw = v.w - mu;
    float ss = dx*dx + dy*dy + dz*dz + dw*dw;
#pragma unroll
    for (int m = 1; m < 64; m <<= 1) ss += __shfl_xor(ss, m);
    float r = rsqrtf(ss * (1.0f / 256.0f) + LN_EPS);

    float4 g4 = *(const float4*)&g[l*4];
    float4 b4 = *(const float4*)&bta[l*4];
    float4 o;
    o.x = dx * r * g4.x + b4.x;
    o.y = dy * r * g4.y + b4.y;
    o.z = dz * r * g4.z + b4.z;
    o.w = dw * r * g4.w + b4.w;
    *(float4*)&X[row*DOUT + l*4] = o;
}

// ---------------------------------------------------------------------------
extern "C" void kernel_launch(void* const* d_in, const int* in_sizes, int n_in,
                              void* d_out, int out_size, void* d_ws, size_t ws_size,
                              hipStream_t stream) {
    const float* X    = (const float*)d_in[0];
    const float* E    = (const float*)d_in[1];
    const float* Wq   = (const float*)d_in[2];
    const float* bq   = (const float*)d_in[3];
    const float* Wk   = (const float*)d_in[4];
    const float* bk   = (const float*)d_in[5];
    const float* Wv   = (const float*)d_in[6];
    const float* bv   = (const float*)d_in[7];
    const float* We   = (const float*)d_in[8];
    // d_in[9] = be: constant over softmax axis -> cancels exactly; dropped
    const float* Wo   = (const float*)d_in[10];
    const float* bo   = (const float*)d_in[11];
    const float* gam  = (const float*)d_in[12];
    const float* bet  = (const float*)d_in[13];
    float* out = (float*)d_out;

    // workspace layout (32 MB total, same footprint as round-1 baseline):
    // Qhi,Qlo,K,Vt bf16 (4 MB each) + V fp32 (8 MB) + AO fp32 (8 MB)
    const size_t TENS = (size_t)NB * NN * DH * NH;   // 2,097,152 elements
    unsigned short* Qhi = (unsigned short*)d_ws;
    unsigned short* Qlo = Qhi + TENS;
    unsigned short* Kb  = Qlo + TENS;
    unsigned short* Vt  = Kb + TENS;
    float* Vf = (float*)(Vt + TENS);
    float* AO = Vf + TENS;

    dim3 gA(NB*NN/64, DOUT/64);
    qkv_kernel<<<gA, 256, 0, stream>>>(X, Wq, bq, Wk, bk, Wv, bv, Qhi, Qlo, Kb, Vf);

    vtrans_kernel<<<NB*NH*(NN/64), 256, 0, stream>>>(Vf, Vt);

    attn_kernel<<<NB*NH*(NN/64), 256, 0, stream>>>(Qhi, Qlo, Kb, Vt, E, We, AO);

    dim3 gC(NB*NN/64, DOUT/64);
    oproj_kernel<<<gC, 256, 0, stream>>>(AO, Wo, bo, X, out);

    ln_kernel<<<NB*NN, 64, 0, stream>>>(out, gam, bet);
}